// Round 6
// baseline (670.746 us; speedup 1.0000x reference)
//
#include <hip/hip_runtime.h>

// Problem constants (B,C,T,V)=(32,128,64,25), N_STEP=8, DILATION=1
#define CC     128
#define TT     64
#define VV     25
#define BB     32
#define PP     (TT * VV)          // 1600 positions per (b, c)
#define CHUNK  (BB * CC * PP)     // 6,553,600 elems per output chunk
#define NSTEP  8
#define PTILE  160                // positions per block tile (640B write segments)
#define NPT    (PP / PTILE)       // 10 tiles per batch -> grid 320, all co-resident

typedef __attribute__((ext_vector_type(8))) __bf16 bf16x8;   // MFMA A/B frag (4 VGPR)
typedef __attribute__((ext_vector_type(4))) float  f32x4;    // MFMA C/D frag

__device__ __forceinline__ float fast_tanh(float x) {
    float e = __expf(2.0f * x);
    return 1.0f - 2.0f * __builtin_amdgcn_rcpf(e + 1.0f);
}

// Split fp32 into truncated-bf16 hi + truncated-bf16 lo (residual <= 2^-16 rel).
__device__ __forceinline__ void bf16_split(float y, unsigned short& h, unsigned short& lo) {
    unsigned int bits = __float_as_uint(y);
    h = (unsigned short)(bits >> 16);
    float r = y - __uint_as_float(bits & 0xffff0000u);
    lo = (unsigned short)(__float_as_uint(r) >> 16);
}

__device__ __forceinline__ float bf16_up(unsigned short u) {
    return __uint_as_float(((unsigned int)u) << 16);
}

// Byte offset of (p, c) in a [PTILE][CC] ushort LDS plane, XOR-swizzled on the
// row index p. b128 frag reads, b64 x_old/publish accesses all row-strided ->
// swizzle spreads 8 rows over distinct 16B slots (~2-way on banks, free).
__device__ __forceinline__ int xb_off(int p, int c) {
    return (p * 256 + c * 2) ^ ((p & 7) << 4) ^ ((p & 8) << 3);
}

// LDS-only barrier: waits own DS ops, does NOT drain vmcnt (global stores stay
// in flight across steps). sched_barrier fences per guide rule #18.
__device__ __forceinline__ void lds_barrier() {
    asm volatile("s_waitcnt lgkmcnt(0)" ::: "memory");
    __builtin_amdgcn_sched_barrier(0);
    __builtin_amdgcn_s_barrier();
    __builtin_amdgcn_sched_barrier(0);
}

// ---- single fused kernel: 8-step Euler, split-bf16 MFMA ----------------------
// Block owns (b, 160-position tile) x all 128 channels. A=W, B=X: D[row=d][col=p].
// fp32 state is NOT kept in registers: the bf16 hi/lo LDS planes (80 KB total)
// ARE the state; x_old is reconstructed as hi+lo (<=2^-17 rel err per step).
// 2 blocks/CU (2x80KB = full 160KB pool); grid 320 = all blocks co-resident.
// Wave w: d-tiles {2w,2w+1} x p-tiles {0..9} = 20 acc tiles, 240 MFMA/step.
__global__ __launch_bounds__(256, 2) void euler_fused(
    const float* __restrict__ z, const float* __restrict__ W,
    const float* __restrict__ bias, float* __restrict__ out)
{
    __shared__ unsigned short XH[PTILE * CC];    // 40960 B bf16-hi state, [p][c] swizzled
    __shared__ unsigned short XL[PTILE * CC];    // 40960 B bf16-lo state

    const int b   = blockIdx.y;
    const int p0  = blockIdx.x * PTILE;
    const int tid = threadIdx.x;
    const int w   = tid >> 6;          // wave 0..3 -> d-tiles {2w, 2w+1}
    const int lr  = tid & 15;          // lane&15: A-row (=d) / B-col (=p) / D-col (=p)
    const int lh  = (tid >> 4) & 3;    // lane>>4: k-group / D-row-group

    // ---- W fragments split in-register from fp32 (A operand: A[row=d][k=c]) ----
    union BF8 { bf16x8 v; unsigned short u[8]; };
    bf16x8 wh[2][4], wl[2][4];
    #pragma unroll
    for (int dt = 0; dt < 2; ++dt) {
        const int d = (2 * w + dt) * 16 + lr;
        #pragma unroll
        for (int ks = 0; ks < 4; ++ks) {
            const float* wp = W + d * CC + ks * 32 + lh * 8;
            f32x4 f0 = *(const f32x4*)wp;
            f32x4 f1 = *(const f32x4*)(wp + 4);
            BF8 th, tl;
            #pragma unroll
            for (int e = 0; e < 4; ++e) bf16_split(f0[e], th.u[e],     tl.u[e]);
            #pragma unroll
            for (int e = 0; e < 4; ++e) bf16_split(f1[e], th.u[4 + e], tl.u[4 + e]);
            wh[dt][ks] = th.v;
            wl[dt][ks] = tl.v;
        }
    }

    // bias per D-row: d = (2w+dt)*16 + lh*4 + j
    float bv[2][4];
    #pragma unroll
    for (int dt = 0; dt < 2; ++dt)
        #pragma unroll
        for (int j = 0; j < 4; ++j)
            bv[dt][j] = bias[(2 * w + dt) * 16 + lh * 4 + j];

    // ---- prologue: cooperative z-tile load -> chunk-0 outputs + XH/XL ----
    const float* zb = z + (size_t)b * CC * PP + p0;
    #pragma unroll
    for (int it = 0; it < 20; ++it) {
        unsigned int slot = it * 256 + tid;         // 5120 float4 slots
        unsigned int c  = slot / 40;                // 40 float4 per 160-pos row
        unsigned int po = (slot % 40) * 4;
        f32x4 v = *(const f32x4*)(zb + (size_t)c * PP + po);
        size_t o = (size_t)(b * CC + c) * PP + p0 + po;
        *(f32x4*)(out + o)                     = v;   // z_shift chunk 0 (= z)
        *(f32x4*)(out + (size_t)9 * CHUNK + o) = v;   // z_cls   chunk 0 (= z)
        #pragma unroll
        for (int e = 0; e < 4; ++e) {
            unsigned short h, lo;
            bf16_split(v[e], h, lo);
            int off = xb_off(po + e, c);
            *(unsigned short*)((char*)XH + off) = h;
            *(unsigned short*)((char*)XL + off) = lo;
        }
    }

    lds_barrier();

    const int swz = ((lr & 7) << 4) ^ ((lr & 8) << 3);

    #pragma unroll 1
    for (int i = 1; i <= NSTEP; ++i) {
        f32x4 acc[10][2];
        #pragma unroll
        for (int pt = 0; pt < 10; ++pt)
            #pragma unroll
            for (int dt = 0; dt < 2; ++dt)
                acc[pt][dt] = (f32x4){0.0f, 0.0f, 0.0f, 0.0f};

        // ---- channel matmul: acc = Wh*Xh + Wh*Xl + Wl*Xh (fp32 accum) ----
        #pragma unroll
        for (int pt = 0; pt < 10; ++pt) {
            #pragma unroll
            for (int ks = 0; ks < 4; ++ks) {
                const int ro = ((pt * 16 + lr) * 256 + ks * 64 + lh * 16) ^ swz;
                bf16x8 bh = *(const bf16x8*)((const char*)XH + ro);
                bf16x8 bl = *(const bf16x8*)((const char*)XL + ro);
                #pragma unroll
                for (int dt = 0; dt < 2; ++dt) {
                    acc[pt][dt] = __builtin_amdgcn_mfma_f32_16x16x32_bf16(wh[dt][ks], bh, acc[pt][dt], 0, 0, 0);
                    acc[pt][dt] = __builtin_amdgcn_mfma_f32_16x16x32_bf16(wh[dt][ks], bl, acc[pt][dt], 0, 0, 0);
                    acc[pt][dt] = __builtin_amdgcn_mfma_f32_16x16x32_bf16(wl[dt][ks], bh, acc[pt][dt], 0, 0, 0);
                }
            }
        }

        // ---- y = x_old + tanh(acc + bias); x_old = hi + lo from LDS ----
        #pragma unroll
        for (int pt = 0; pt < 10; ++pt)
            #pragma unroll
            for (int dt = 0; dt < 2; ++dt) {
                const int off = xb_off(pt * 16 + lr, (2 * w + dt) * 16 + lh * 4);
                ushort4 h4 = *(const ushort4*)((const char*)XH + off);
                ushort4 l4 = *(const ushort4*)((const char*)XL + off);
                const unsigned short hu[4] = {h4.x, h4.y, h4.z, h4.w};
                const unsigned short lu[4] = {l4.x, l4.y, l4.z, l4.w};
                #pragma unroll
                for (int j = 0; j < 4; ++j) {
                    float xo = bf16_up(hu[j]) + bf16_up(lu[j]);
                    acc[pt][dt][j] = xo + fast_tanh(acc[pt][dt][j] + bv[dt][j]);
                }
            }

        if (i < NSTEP) {
            lds_barrier();   // all reads of old state done before overwrite

            // ---- publish new bf16 hi/lo state: row-contiguous ushort4 ----
            #pragma unroll
            for (int pt = 0; pt < 10; ++pt)
                #pragma unroll
                for (int dt = 0; dt < 2; ++dt) {
                    ushort4 hv, lv;
                    bf16_split(acc[pt][dt][0], hv.x, lv.x);
                    bf16_split(acc[pt][dt][1], hv.y, lv.y);
                    bf16_split(acc[pt][dt][2], hv.z, lv.z);
                    bf16_split(acc[pt][dt][3], hv.w, lv.w);
                    const int off = xb_off(pt * 16 + lr, (2 * w + dt) * 16 + lh * 4);
                    *(ushort4*)((char*)XH + off) = hv;
                    *(ushort4*)((char*)XL + off) = lv;
                }

            lds_barrier();   // publish visible; stores below overlap next step
        }

        // ---- global stores for chunk i (cached, fire-and-forget) ----
        // Coalesced across lr-lanes: 16 consecutive p per 64B burst, per d row;
        // block footprint per chunk-step: 128 rows x 640B contiguous segments.
        const size_t shiftBase = (size_t)i * CHUNK;
        const size_t clsBase   = (size_t)(9 + i) * CHUNK;
        const int s = VV * i;   // flat-position shift (t -> t+i)
        const bool fast = (p0 >= s) && (p0 + PTILE + s <= PP);   // block-uniform
        #pragma unroll
        for (int pt = 0; pt < 10; ++pt) {
            const int p = p0 + pt * 16 + lr;
            #pragma unroll
            for (int dt = 0; dt < 2; ++dt) {
                #pragma unroll
                for (int j = 0; j < 4; ++j) {
                    const int d = (2 * w + dt) * 16 + lh * 4 + j;
                    const size_t row = (size_t)(b * CC + d) * PP;
                    const float y = acc[pt][dt][j];
                    out[clsBase + row + p] = y;                       // z_cls chunk i
                    if (fast) {
                        out[shiftBase + row + p + s] = y;             // z_shift chunk i
                    } else {
                        const int q = p + s;
                        if (q < PP) out[shiftBase + row + q] = y;
                        if (p < s)  out[shiftBase + row + p] = 0.0f;  // leading zeros
                    }
                }
            }
        }
    }
}

extern "C" void kernel_launch(void* const* d_in, const int* in_sizes, int n_in,
                              void* d_out, int out_size, void* d_ws, size_t ws_size,
                              hipStream_t stream) {
    const float* z    = (const float*)d_in[0];   // (32,128,64,25) fp32
    const float* W    = (const float*)d_in[1];   // (128,128) fp32
    const float* bias = (const float*)d_in[2];   // (128,) fp32
    float* out = (float*)d_out;                  // 18 * CHUNK fp32

    hipLaunchKernelGGL(euler_fused, dim3(NPT, BB), dim3(256), 0, stream, z, W, bias, out);
}